// Round 1
// baseline (5885.141 us; speedup 1.0000x reference)
//
#include <hip/hip_runtime.h>
#include <math.h>

// Problem constants (fixed by the reference)
#define BB 2
#define LL 4
#define CC 128
#define HH 48
#define WW 176
#define HWW (HH*WW)   // 8448

// Tiling
#define TPY 16
#define TPX 16
#define EXT 18        // TPY+2 halo
#define TSTR 20       // LDS row stride (pad)

// ---------------------------------------------------------------------------
// Kernel 0: affine inverse for all (b,i,j) pairs  -> ainv[(b*L+i)*L+j]*8
// ---------------------------------------------------------------------------
__global__ void ainv_kernel(const float* __restrict__ T, float* __restrict__ ainv)
{
    int idx = threadIdx.x;
    if (idx >= BB*LL*LL) return;
    const float* t = T + idx*16;
    float R00=t[0], R01=t[1], t0=t[3];
    float R10=t[4], R11=t[5], t1=t[7];
    float tx = t0 * 0.625f;              // / (RATIO*DS) = /1.6
    float ty = t1 * 0.625f;
    const float cx = WW/2.0f, cy = HH/2.0f;
    float ftx = cx - (R00*cx + R01*cy) + tx;
    float fty = cy - (R10*cx + R11*cy) + ty;
    float det = R00*R11 - R01*R10;
    float inv = 1.0f/det;
    float i00 =  R11*inv, i01 = -R01*inv, i10 = -R10*inv, i11 = R00*inv;
    float tix = -(i00*ftx + i01*fty);
    float tiy = -(i10*ftx + i11*fty);
    float* a = ainv + idx*8;
    a[0]=i00; a[1]=i01; a[2]=tix; a[3]=i10; a[4]=i11; a[5]=tiy;
    a[6]=0.f; a[7]=0.f;
}

// ---------------------------------------------------------------------------
// Kernel 1: fused warp + msg conv + roi-weighted sum over l2  -> agg (already /rec)
// agg[((b*n_l1+l1)*C + oc)*HW + pix]
// ---------------------------------------------------------------------------
__global__ __launch_bounds__(256)
void msg_agg_kernel(const float* __restrict__ feat, const float* __restrict__ ainv,
                    const float* __restrict__ mask, const int* __restrict__ reclen,
                    const float* __restrict__ Wm, const float* __restrict__ bm,
                    float* __restrict__ agg, int n_l1)
{
    int z = blockIdx.z;
    int b = z / n_l1, l1 = z % n_l1;
    if (!(l1 == 0 || mask[b*LL + l1] != 0.f)) return;   // output never consumed

    int trow = blockIdx.x / (WW/TPX);
    int tcol = blockIdx.x % (WW/TPX);
    int py0 = trow*TPY, px0 = tcol*TPX;
    int oc0 = blockIdx.y * 32;

    int th = threadIdx.x;
    int ly = th >> 4, lx = th & 15;
    int gy = py0 + ly, gx = px0 + lx;

    __shared__ float tile[EXT*TSTR];
    __shared__ float tw0[EXT*EXT], tw1[EXT*EXT], tw2[EXT*EXT], tw3[EXT*EXT];
    __shared__ int   to0[EXT*EXT], to1[EXT*EXT], to2[EXT*EXT], to3[EXT*EXT];

    float m[LL];
    #pragma unroll
    for (int j=0;j<LL;j++) m[j] = mask[b*LL+j];

    // per-pixel roi factors; fac[0] = sum over l2 (multiplies ego conv + bias)
    float fac[5];
    fac[0] = 0.f;
    #pragma unroll
    for (int l2=0; l2<LL; l2++) {
        float r = 0.f;
        if (m[l2] != 0.f) {
            const float* a = ainv + ((size_t)((b*LL + l2)*LL + l1))*8;
            float sx = a[0]*(float)gx + a[1]*(float)gy + a[2];
            float sy = a[3]*(float)gx + a[4]*(float)gy + a[5];
            float x0 = floorf(sx), y0 = floorf(sy);
            float wx = sx-x0, wy = sy-y0;
            int xi = (int)x0, yi = (int)y0;
            bool vx0 = (xi >= 0) && (xi <= WW-1);
            bool vx1 = (xi+1 >= 0) && (xi+1 <= WW-1);
            bool vy0 = (yi >= 0) && (yi <= HH-1);
            bool vy1 = (yi+1 >= 0) && (yi+1 <= HH-1);
            r = (vx0&&vy0 ? (1.f-wx)*(1.f-wy) : 0.f)
              + (vx1&&vy0 ? wx*(1.f-wy)       : 0.f)
              + (vx0&&vy1 ? (1.f-wx)*wy       : 0.f)
              + (vx1&&vy1 ? wx*wy             : 0.f);
            r *= m[l2];
        }
        fac[1+l2] = r;
        fac[0] += r;
    }

    float total[32];
    #pragma unroll
    for (int oc=0; oc<32; oc++) total[oc] = fac[0]*bm[oc0+oc];

    for (int s=0; s<5; s++) {
        int l2 = s-1;
        if (s > 0 && m[l2] == 0.f) continue;            // block-uniform

        const float* src = feat + (size_t)((b*LL + (s==0 ? l1 : l2)) * CC) * HWW;

        __syncthreads();   // previous source's readers done
        if (s == 0) {
            for (int i=th; i<EXT*EXT; i+=256) {
                int ey=i/EXT, ex=i%EXT;
                int yy=py0+ey-1, xx=px0+ex-1;
                bool in = (yy>=0 && yy<HH && xx>=0 && xx<WW);
                to0[i] = in ? yy*WW+xx : 0;
                tw0[i] = in ? 1.f : 0.f;
                tw1[i]=0.f; tw2[i]=0.f; tw3[i]=0.f;
                to1[i]=0; to2[i]=0; to3[i]=0;
            }
        } else {
            const float* a = ainv + ((size_t)((b*LL + l2)*LL + l1))*8;
            float a0=a[0],a1=a[1],a2=a[2],a3=a[3],a4=a[4],a5=a[5];
            for (int i=th; i<EXT*EXT; i+=256) {
                int ey=i/EXT, ex=i%EXT;
                int yy=py0+ey-1, xx=px0+ex-1;
                bool in = (yy>=0 && yy<HH && xx>=0 && xx<WW);
                float w00=0.f,w10=0.f,w01=0.f,w11=0.f;
                int o00=0,o10=0,o01=0,o11=0;
                if (in) {
                    float sx = a0*(float)xx + a1*(float)yy + a2;
                    float sy = a3*(float)xx + a4*(float)yy + a5;
                    float x0 = floorf(sx), y0 = floorf(sy);
                    float wx = sx-x0, wy = sy-y0;
                    int xi=(int)x0, yi=(int)y0;
                    bool vx0 = (xi>=0)&&(xi<WW);
                    bool vx1 = (xi+1>=0)&&(xi+1<WW);
                    bool vy0 = (yi>=0)&&(yi<HH);
                    bool vy1 = (yi+1>=0)&&(yi+1<HH);
                    int xc0=min(max(xi,0),WW-1),   xc1=min(max(xi+1,0),WW-1);
                    int yc0=min(max(yi,0),HH-1),   yc1=min(max(yi+1,0),HH-1);
                    o00=yc0*WW+xc0; o10=yc0*WW+xc1; o01=yc1*WW+xc0; o11=yc1*WW+xc1;
                    w00 = (vx0&&vy0)?(1.f-wx)*(1.f-wy):0.f;
                    w10 = (vx1&&vy0)?wx*(1.f-wy):0.f;
                    w01 = (vx0&&vy1)?(1.f-wx)*wy:0.f;
                    w11 = (vx1&&vy1)?wx*wy:0.f;
                }
                tw0[i]=w00; tw1[i]=w10; tw2[i]=w01; tw3[i]=w11;
                to0[i]=o00; to1[i]=o10; to2[i]=o01; to3[i]=o11;
            }
        }

        float acc[32];
        #pragma unroll
        for (int oc=0;oc<32;oc++) acc[oc]=0.f;

        for (int cin=0; cin<CC; cin++) {
            const float* p = src + (size_t)cin*HWW;
            __syncthreads();   // prev tile readers done (also covers tap setup)
            for (int i=th; i<EXT*EXT; i+=256) {
                int ey=i/EXT, ex=i%EXT;
                float v = tw0[i]*p[to0[i]] + tw1[i]*p[to1[i]]
                        + tw2[i]*p[to2[i]] + tw3[i]*p[to3[i]];
                tile[ey*TSTR+ex] = v;
            }
            __syncthreads();
            float r00=tile[(ly+0)*TSTR+lx+0], r01=tile[(ly+0)*TSTR+lx+1], r02=tile[(ly+0)*TSTR+lx+2];
            float r10=tile[(ly+1)*TSTR+lx+0], r11=tile[(ly+1)*TSTR+lx+1], r12=tile[(ly+1)*TSTR+lx+2];
            float r20=tile[(ly+2)*TSTR+lx+0], r21=tile[(ly+2)*TSTR+lx+1], r22=tile[(ly+2)*TSTR+lx+2];
            int ci = (s==0) ? (CC + cin) : cin;
            const float* wbase = Wm + ((size_t)oc0*(2*CC) + ci)*9;
            #pragma unroll
            for (int oc=0; oc<32; oc++) {
                const float* wp = wbase + (size_t)oc*(2*CC)*9;   // wave-uniform -> s_load
                float a = acc[oc];
                a = fmaf(wp[0],r00,a); a = fmaf(wp[1],r01,a); a = fmaf(wp[2],r02,a);
                a = fmaf(wp[3],r10,a); a = fmaf(wp[4],r11,a); a = fmaf(wp[5],r12,a);
                a = fmaf(wp[6],r20,a); a = fmaf(wp[7],r21,a); a = fmaf(wp[8],r22,a);
                acc[oc] = a;
            }
        }
        float f = fac[s];
        #pragma unroll
        for (int oc=0;oc<32;oc++) total[oc] += acc[oc]*f;
    }

    float invrec = 1.0f / (float)reclen[b];
    size_t outbase = ((size_t)(b*n_l1 + l1)*CC)*HWW + (size_t)gy*WW + gx;
    #pragma unroll
    for (int oc=0; oc<32; oc++) {
        agg[outbase + (size_t)(oc0+oc)*HWW] = total[oc]*invrec;
    }
}

// ---------------------------------------------------------------------------
// Kernel 2: GRU update. u = sigmoid(convU([feat,agg])), cand = tanh(convC([feat,agg]))
// out = u*cand.  Only second half of W_gates rows / first 2C input cols used (h==0).
// ---------------------------------------------------------------------------
__global__ __launch_bounds__(256)
void gru_kernel(const float* __restrict__ feat, const float* __restrict__ agg,
                const float* __restrict__ mask,
                const float* __restrict__ Wg, const float* __restrict__ bg,
                const float* __restrict__ Wc, const float* __restrict__ bc,
                float* __restrict__ out, int n_l1)
{
    int z = blockIdx.z;
    int b = z / n_l1, l1 = z % n_l1;
    if (!(l1 == 0 || mask[b*LL + l1] != 0.f)) return;

    int trow = blockIdx.x / (WW/TPX);
    int tcol = blockIdx.x % (WW/TPX);
    int py0 = trow*TPY, px0 = tcol*TPX;
    int oc0 = blockIdx.y * 16;
    int th = threadIdx.x;
    int ly = th >> 4, lx = th & 15;
    int gy = py0 + ly, gx = px0 + lx;

    __shared__ float tile[EXT*TSTR];

    float accU[16], accC[16];
    #pragma unroll
    for (int oc=0;oc<16;oc++){ accU[oc]=0.f; accC[oc]=0.f; }

    for (int cin=0; cin<2*CC; cin++) {
        const float* p = (cin < CC)
            ? feat + ((size_t)(b*LL + l1)*CC + cin)*HWW
            : agg  + ((size_t)(b*n_l1 + l1)*CC + (cin-CC))*HWW;
        __syncthreads();
        for (int i=th; i<EXT*EXT; i+=256) {
            int ey=i/EXT, ex=i%EXT;
            int yy=py0+ey-1, xx=px0+ex-1;
            tile[ey*TSTR+ex] = (yy>=0&&yy<HH&&xx>=0&&xx<WW) ? p[yy*WW+xx] : 0.f;
        }
        __syncthreads();
        float r00=tile[(ly+0)*TSTR+lx+0], r01=tile[(ly+0)*TSTR+lx+1], r02=tile[(ly+0)*TSTR+lx+2];
        float r10=tile[(ly+1)*TSTR+lx+0], r11=tile[(ly+1)*TSTR+lx+1], r12=tile[(ly+1)*TSTR+lx+2];
        float r20=tile[(ly+2)*TSTR+lx+0], r21=tile[(ly+2)*TSTR+lx+1], r22=tile[(ly+2)*TSTR+lx+2];
        const float* wub = Wg + ((size_t)(CC + oc0)*(3*CC) + cin)*9;   // u = rows C..2C-1
        const float* wcb = Wc + ((size_t)oc0*(3*CC) + cin)*9;
        #pragma unroll
        for (int oc=0; oc<16; oc++) {
            const float* wu = wub + (size_t)oc*(3*CC)*9;
            const float* wc = wcb + (size_t)oc*(3*CC)*9;
            float a = accU[oc];
            a = fmaf(wu[0],r00,a); a = fmaf(wu[1],r01,a); a = fmaf(wu[2],r02,a);
            a = fmaf(wu[3],r10,a); a = fmaf(wu[4],r11,a); a = fmaf(wu[5],r12,a);
            a = fmaf(wu[6],r20,a); a = fmaf(wu[7],r21,a); a = fmaf(wu[8],r22,a);
            accU[oc] = a;
            float cacc = accC[oc];
            cacc = fmaf(wc[0],r00,cacc); cacc = fmaf(wc[1],r01,cacc); cacc = fmaf(wc[2],r02,cacc);
            cacc = fmaf(wc[3],r10,cacc); cacc = fmaf(wc[4],r11,cacc); cacc = fmaf(wc[5],r12,cacc);
            cacc = fmaf(wc[6],r20,cacc); cacc = fmaf(wc[7],r21,cacc); cacc = fmaf(wc[8],r22,cacc);
            accC[oc] = cacc;
        }
    }

    size_t outbase = ((size_t)(b*n_l1 + l1)*CC)*HWW + (size_t)gy*WW + gx;
    #pragma unroll
    for (int oc=0; oc<16; oc++) {
        float u  = 1.f/(1.f + expf(-(accU[oc] + bg[CC + oc0 + oc])));
        float cd = tanhf(accC[oc] + bc[oc0 + oc]);
        out[outbase + (size_t)(oc0+oc)*HWW] = u*cd;
    }
}

// ---------------------------------------------------------------------------
// Kernel 3: final 1x1 MLP on feat2[b,0]  ->  out[b,o,h,w]
// ---------------------------------------------------------------------------
__global__ __launch_bounds__(256)
void mlp_kernel(const float* __restrict__ feat2, const float* __restrict__ Wm,
                const float* __restrict__ bmlp, float* __restrict__ out)
{
    int b = blockIdx.z;
    int pix = blockIdx.x*256 + threadIdx.x;   // 8448 = 33*256
    int oc0 = blockIdx.y*16;
    float acc[16];
    #pragma unroll
    for (int oc=0;oc<16;oc++) acc[oc]=0.f;
    for (int c=0;c<CC;c++) {
        float v = feat2[((size_t)b*CC + c)*HWW + pix];
        #pragma unroll
        for (int oc=0;oc<16;oc++)
            acc[oc] = fmaf(v, Wm[(size_t)(oc0+oc)*CC + c], acc[oc]);
    }
    #pragma unroll
    for (int oc=0;oc<16;oc++)
        out[((size_t)b*CC + oc0+oc)*HWW + pix] = acc[oc] + bmlp[oc0+oc];
}

// ---------------------------------------------------------------------------
extern "C" void kernel_launch(void* const* d_in, const int* in_sizes, int n_in,
                              void* d_out, int out_size, void* d_ws, size_t ws_size,
                              hipStream_t stream)
{
    const float* x     = (const float*)d_in[0];
    const float* mask  = (const float*)d_in[1];
    const float* T     = (const float*)d_in[2];
    const int*   recl  = (const int*)  d_in[3];
    const float* Wmsg  = (const float*)d_in[4];
    const float* bmsg  = (const float*)d_in[5];
    const float* Wg    = (const float*)d_in[6];
    const float* bg    = (const float*)d_in[7];
    const float* Wc    = (const float*)d_in[8];
    const float* bc    = (const float*)d_in[9];
    const float* Wmlp  = (const float*)d_in[10];
    const float* bmlp  = (const float*)d_in[11];
    float* out = (float*)d_out;

    float* ws    = (float*)d_ws;
    float* ainv  = ws;                                   // 256 floats
    float* feat1 = ws + 256;                             // B*L*C*HW
    float* agg   = feat1 + (size_t)BB*LL*CC*HWW;         // B*L*C*HW
    float* feat2 = agg   + (size_t)BB*LL*CC*HWW;         // B*C*HW

    ainv_kernel<<<1, 64, 0, stream>>>(T, ainv);

    // ---- iteration 1 (all l1; masked-out pairs skipped in-kernel) ----
    msg_agg_kernel<<<dim3(33, 4, BB*LL), 256, 0, stream>>>(
        x, ainv, mask, recl, Wmsg, bmsg, agg, LL);
    gru_kernel<<<dim3(33, 8, BB*LL), 256, 0, stream>>>(
        x, agg, mask, Wg, bg, Wc, bc, feat1, LL);

    // ---- iteration 2 (only l1 = 0 is ever consumed) ----
    msg_agg_kernel<<<dim3(33, 4, BB), 256, 0, stream>>>(
        feat1, ainv, mask, recl, Wmsg, bmsg, agg, 1);
    gru_kernel<<<dim3(33, 8, BB), 256, 0, stream>>>(
        feat1, agg, mask, Wg, bg, Wc, bc, feat2, 1);

    // ---- final MLP ----
    mlp_kernel<<<dim3(33, 8, BB), 256, 0, stream>>>(feat2, Wmlp, bmlp, out);
}

// Round 2
// 694.265 us; speedup vs baseline: 8.4768x; 8.4768x over previous
//
#include <hip/hip_runtime.h>
#include <math.h>

#define BB 2
#define LL 4
#define CC 128
#define HH 48
#define WWID 176
#define HW 8448   // 48*176

typedef __attribute__((ext_vector_type(8))) short bf16x8;
typedef __attribute__((ext_vector_type(4))) float f32x4;
typedef __attribute__((ext_vector_type(4))) unsigned int u32x4;
typedef __attribute__((ext_vector_type(2))) unsigned int u32x2;
typedef __attribute__((ext_vector_type(4))) short short4v;

__device__ __forceinline__ float b2f(short s){
    unsigned int u = ((unsigned int)(unsigned short)s) << 16;
    union { unsigned int u; float f; } c; c.u = u; return c.f;
}
__device__ __forceinline__ unsigned short f2b(float f){
    union { float f; unsigned int u; } c; c.f = f;
    unsigned int r = c.u + 0x7fffu + ((c.u >> 16) & 1u);
    return (unsigned short)(r >> 16);
}

// ---------------------------------------------------------------------------
// Kernel 0: affine inverse for all (b,i,j) pairs  -> ainv[(b*L+i)*L+j]*8
// ---------------------------------------------------------------------------
__global__ void ainv_kernel(const float* __restrict__ T, float* __restrict__ ainv)
{
    int idx = threadIdx.x;
    if (idx >= BB*LL*LL) return;
    const float* t = T + idx*16;
    float R00=t[0], R01=t[1], t0=t[3];
    float R10=t[4], R11=t[5], t1=t[7];
    float tx = t0 * 0.625f;              // / (RATIO*DS) = /1.6
    float ty = t1 * 0.625f;
    const float cx = WWID/2.0f, cy = HH/2.0f;
    float ftx = cx - (R00*cx + R01*cy) + tx;
    float fty = cy - (R10*cx + R11*cy) + ty;
    float det = R00*R11 - R01*R10;
    float inv = 1.0f/det;
    float i00 =  R11*inv, i01 = -R01*inv, i10 = -R10*inv, i11 = R00*inv;
    float tix = -(i00*ftx + i01*fty);
    float tiy = -(i10*ftx + i11*fty);
    float* a = ainv + idx*8;
    a[0]=i00; a[1]=i01; a[2]=tix; a[3]=i10; a[4]=i11; a[5]=tiy;
    a[6]=0.f; a[7]=0.f;
}

// ---------------------------------------------------------------------------
// Repack conv weights (OIHW fp32) -> [tap][oc 128][cin 256] bf16
// ---------------------------------------------------------------------------
__global__ __launch_bounds__(256)
void repack_kernel(const float* __restrict__ src, short* __restrict__ dst,
                   int oc_off, int stride)
{
    int idx = blockIdx.x*256 + threadIdx.x;
    if (idx >= 9*128*256) return;
    int cin = idx & 255;
    int oc  = (idx >> 8) & 127;
    int tap = idx >> 15;
    dst[(tap*128 + oc)*256 + cin] =
        (short)f2b(src[((size_t)(oc_off+oc)*stride + cin)*9 + tap]);
}

// ---------------------------------------------------------------------------
// x [bl][c][pix] fp32  ->  xT [bl][pix][c] bf16
// ---------------------------------------------------------------------------
__global__ __launch_bounds__(256)
void to_bf16T_kernel(const float* __restrict__ x, short* __restrict__ xT)
{
    int bl = blockIdx.y;
    int pix = blockIdx.x*256 + threadIdx.x;   // grid.x = 33
    const float* src = x + (size_t)bl*CC*HW + pix;
    short* dst = xT + (size_t)bl*HW*CC + (size_t)pix*CC;
    for (int g = 0; g < 8; ++g) {
        unsigned int pk[8];
        #pragma unroll
        for (int c2 = 0; c2 < 8; ++c2) {
            float v0 = src[(size_t)(g*16 + 2*c2    )*HW];
            float v1 = src[(size_t)(g*16 + 2*c2 + 1)*HW];
            pk[c2] = (unsigned int)f2b(v0) | ((unsigned int)f2b(v1) << 16);
        }
        u32x4 w0 = {pk[0],pk[1],pk[2],pk[3]};
        u32x4 w1 = {pk[4],pk[5],pk[6],pk[7]};
        *(u32x4*)(dst + g*16    ) = w0;
        *(u32x4*)(dst + g*16 + 8) = w1;
    }
}

// ---------------------------------------------------------------------------
// roi factor maps: fac[slot=(b,l2,l1)][pix]  (already * mask[l2])
// ---------------------------------------------------------------------------
__global__ __launch_bounds__(256)
void fac_kernel(const float* __restrict__ ainv, const float* __restrict__ mask,
                float* __restrict__ fac)
{
    int slot = blockIdx.y;                    // (b<<4)|(l2<<2)|l1
    int pix = blockIdx.x*256 + threadIdx.x;
    int b = slot >> 4, l2 = (slot >> 2) & 3;
    float mk = mask[b*LL + l2];
    const float* a = ainv + slot*8;
    float gx = (float)(pix % WWID), gy = (float)(pix / WWID);
    float sx = a[0]*gx + a[1]*gy + a[2];
    float sy = a[3]*gx + a[4]*gy + a[5];
    float x0 = floorf(sx), y0 = floorf(sy);
    float wx = sx-x0, wy = sy-y0;
    int xi=(int)x0, yi=(int)y0;
    bool vx0 = xi>=0 && xi<WWID, vx1 = xi+1>=0 && xi+1<WWID;
    bool vy0 = yi>=0 && yi<HH,   vy1 = yi+1>=0 && yi+1<HH;
    float r = (vx0&&vy0?(1.f-wx)*(1.f-wy):0.f) + (vx1&&vy0?wx*(1.f-wy):0.f)
            + (vx0&&vy1?(1.f-wx)*wy:0.f)       + (vx1&&vy1?wx*wy:0.f);
    fac[(size_t)slot*HW + pix] = r*mk;
}

// ===========================================================================
// MFMA conv common geometry:
//   block 256 thr = 4 waves; block tile = 128 oc x (8y x 16x) pixels
//   wave (wr,wc): 64 oc x (4y x 16x).  16x16x32 bf16 MFMA, K = cin.
//   LDS input region: 10y' x 18x' halo, 128 cin bf16, row=pos (256B),
//   swizzle byte ^= ((pos&7)<<4).
// ===========================================================================

// fused warp + msg conv + roi-weighted aggregation (already / rec)
__global__ __launch_bounds__(256,2)
void msg_mfma_kernel(const short* __restrict__ featT, const float* __restrict__ ainv,
                     const float* __restrict__ fac, const float* __restrict__ mask,
                     const int* __restrict__ reclen,
                     const short* __restrict__ WmT, const float* __restrict__ bm,
                     short* __restrict__ aggT, int n_l1)
{
    int z = blockIdx.z;
    int b = z / n_l1, l1 = z % n_l1;
    if (l1 != 0 && mask[b*LL + l1] == 0.f) return;

    int ty = blockIdx.x / 11, tx = blockIdx.x % 11;
    int y0 = ty*8, x0 = tx*16;
    int tid = threadIdx.x;
    int wid = tid >> 6, lane = tid & 63;
    int wr = wid >> 1, wc = wid & 1;
    int l15 = lane & 15, hi = lane >> 4;

    __shared__ short lt[180*128];

    float m2[LL];
    #pragma unroll
    for (int j=0;j<LL;++j) m2[j] = mask[b*LL+j];

    // sum of fac over active l2, per pixel-frag n
    float fvs[4];
    #pragma unroll
    for (int n=0;n<4;++n) fvs[n]=0.f;
    for (int l2=0;l2<LL;++l2) {
        if (m2[l2]==0.f) continue;
        const float* fp = fac + ((size_t)((b*LL+l2)*LL+l1))*HW;
        #pragma unroll
        for (int n=0;n<4;++n)
            fvs[n] += fp[(y0 + wc*4 + n)*WWID + x0 + l15];
    }

    // total init = facsum * bias
    f32x4 total[4][4];
    #pragma unroll
    for (int m=0;m<4;++m) {
        f32x4 bm4 = *(const f32x4*)(bm + wr*64 + m*16 + hi*4);
        #pragma unroll
        for (int n=0;n<4;++n) total[m][n] = bm4 * fvs[n];
    }

    for (int s = 0; s < 5; ++s) {
        int l2 = s-1;
        if (s>0 && m2[l2]==0.f) continue;
        const short* src = featT + (size_t)(b*LL + (s==0 ? l1 : l2))*HW*CC;
        float a0=0,a1=0,a2=0,a3=0,a4=0,a5=0;
        if (s>0){
            const float* a6 = ainv + ((b*LL + l2)*LL + l1)*8;
            a0=a6[0];a1=a6[1];a2=a6[2];a3=a6[3];a4=a6[4];a5=a6[5];
        }
        __syncthreads();     // previous source's readers done
        for (int i = tid; i < 180*16; i += 256) {
            int row = i >> 4, ch = i & 15;
            int yy = row / 18, xx = row - yy*18;
            int gy = y0 - 1 + yy, gx = x0 - 1 + xx;
            u32x4 val = {0,0,0,0};
            if (gy>=0 && gy<HH && gx>=0 && gx<WWID) {
                if (s == 0) {
                    val = *(const u32x4*)(src + (size_t)(gy*WWID+gx)*CC + ch*8);
                } else {
                    float sx = a0*(float)gx + a1*(float)gy + a2;
                    float sy = a3*(float)gx + a4*(float)gy + a5;
                    float xf = floorf(sx), yf = floorf(sy);
                    float wx = sx-xf, wyv = sy-yf;
                    int xi=(int)xf, yi=(int)yf;
                    bool vx0=xi>=0&&xi<WWID, vx1=xi+1>=0&&xi+1<WWID;
                    bool vy0=yi>=0&&yi<HH,   vy1=yi+1>=0&&yi+1<HH;
                    int xc0=min(max(xi,0),WWID-1), xc1=min(max(xi+1,0),WWID-1);
                    int yc0=min(max(yi,0),HH-1),   yc1=min(max(yi+1,0),HH-1);
                    float w00=(vx0&&vy0)?(1.f-wx)*(1.f-wyv):0.f;
                    float w10=(vx1&&vy0)?wx*(1.f-wyv):0.f;
                    float w01=(vx0&&vy1)?(1.f-wx)*wyv:0.f;
                    float w11=(vx1&&vy1)?wx*wyv:0.f;
                    bf16x8 t00 = *(const bf16x8*)(src + (size_t)(yc0*WWID+xc0)*CC + ch*8);
                    bf16x8 t10 = *(const bf16x8*)(src + (size_t)(yc0*WWID+xc1)*CC + ch*8);
                    bf16x8 t01 = *(const bf16x8*)(src + (size_t)(yc1*WWID+xc0)*CC + ch*8);
                    bf16x8 t11 = *(const bf16x8*)(src + (size_t)(yc1*WWID+xc1)*CC + ch*8);
                    unsigned int po[4];
                    #pragma unroll
                    for (int j=0;j<8;j+=2) {
                        float f0 = w00*b2f(t00[j]) + w10*b2f(t10[j])
                                 + w01*b2f(t01[j]) + w11*b2f(t11[j]);
                        float f1 = w00*b2f(t00[j+1]) + w10*b2f(t10[j+1])
                                 + w01*b2f(t01[j+1]) + w11*b2f(t11[j+1]);
                        po[j>>1] = (unsigned int)f2b(f0) | ((unsigned int)f2b(f1)<<16);
                    }
                    val[0]=po[0]; val[1]=po[1]; val[2]=po[2]; val[3]=po[3];
                }
            }
            int byte = (row*256 + ch*16) ^ ((row&7)<<4);
            *(u32x4*)((char*)lt + byte) = val;
        }
        __syncthreads();

        f32x4 sacc[4][4];
        #pragma unroll
        for (int m=0;m<4;++m)
            #pragma unroll
            for (int n=0;n<4;++n) sacc[m][n] = (f32x4){0.f,0.f,0.f,0.f};

        int cinoff = (s==0) ? 128 : 0;
        for (int tap=0; tap<9; ++tap) {
            int dy = tap/3, dx = tap - dy*3;
            const short* wt = WmT + ((tap*128 + wr*64 + l15)*256 + cinoff + hi*8);
            #pragma unroll
            for (int kk=0; kk<4; ++kk) {
                bf16x8 av[4];
                #pragma unroll
                for (int m=0;m<4;++m)
                    av[m] = *(const bf16x8*)(wt + m*16*256 + kk*32);
                bf16x8 bv[4];
                #pragma unroll
                for (int n=0;n<4;++n) {
                    int pos = (wc*4 + n + dy)*18 + dx + l15;
                    int byte = (pos*256 + kk*64 + hi*16) ^ ((pos&7)<<4);
                    bv[n] = *(const bf16x8*)((const char*)lt + byte);
                }
                #pragma unroll
                for (int m=0;m<4;++m)
                    #pragma unroll
                    for (int n=0;n<4;++n)
                        sacc[m][n] = __builtin_amdgcn_mfma_f32_16x16x32_bf16(
                            av[m], bv[n], sacc[m][n], 0, 0, 0);
            }
        }

        // fold with per-pixel scale
        float fsc[4];
        if (s == 0) {
            #pragma unroll
            for (int n=0;n<4;++n) fsc[n] = fvs[n];
        } else {
            const float* fp = fac + ((size_t)((b*LL+l2)*LL+l1))*HW;
            #pragma unroll
            for (int n=0;n<4;++n)
                fsc[n] = fp[(y0 + wc*4 + n)*WWID + x0 + l15];
        }
        #pragma unroll
        for (int m=0;m<4;++m)
            #pragma unroll
            for (int n=0;n<4;++n)
                total[m][n] += sacc[m][n] * fsc[n];
    }

    float invrec = 1.0f / (float)reclen[b];
    short* outp = aggT + (size_t)(b*n_l1 + l1)*HW*CC;
    #pragma unroll
    for (int m=0;m<4;++m)
        #pragma unroll
        for (int n=0;n<4;++n) {
            int pix = (y0 + wc*4 + n)*WWID + x0 + l15;
            int oc  = wr*64 + m*16 + hi*4;
            f32x4 v = total[m][n] * invrec;
            u32x2 pk;
            pk[0] = (unsigned int)f2b(v[0]) | ((unsigned int)f2b(v[1])<<16);
            pk[1] = (unsigned int)f2b(v[2]) | ((unsigned int)f2b(v[3])<<16);
            *(u32x2*)(outp + (size_t)pix*CC + oc) = pk;
        }
}

// GRU conv: ACT=0: u=sigmoid(conv+b) -> uT ; ACT=1: out=tanh(conv+b)*u -> outT
template<int ACT>
__global__ __launch_bounds__(256,2)
void gru_mfma_kernel(const short* __restrict__ featT, const short* __restrict__ aggT,
                     const float* __restrict__ mask,
                     const short* __restrict__ WT, const float* __restrict__ bias,
                     const short* __restrict__ uT_in, short* __restrict__ outT,
                     int n_l1)
{
    int z = blockIdx.z;
    int b = z / n_l1, l1 = z % n_l1;
    if (l1 != 0 && mask[b*LL + l1] == 0.f) return;

    int ty = blockIdx.x / 11, tx = blockIdx.x % 11;
    int y0 = ty*8, x0 = tx*16;
    int tid = threadIdx.x;
    int wid = tid >> 6, lane = tid & 63;
    int wr = wid >> 1, wc = wid & 1;
    int l15 = lane & 15, hi = lane >> 4;

    __shared__ short lt[180*128];

    f32x4 acc[4][4];
    #pragma unroll
    for (int m=0;m<4;++m)
        #pragma unroll
        for (int n=0;n<4;++n) acc[m][n] = (f32x4){0.f,0.f,0.f,0.f};

    for (int s = 0; s < 2; ++s) {
        const short* src = (s==0) ? featT + (size_t)(b*LL + l1)*HW*CC
                                  : aggT  + (size_t)(b*n_l1 + l1)*HW*CC;
        __syncthreads();
        for (int i = tid; i < 180*16; i += 256) {
            int row = i >> 4, ch = i & 15;
            int yy = row / 18, xx = row - yy*18;
            int gy = y0 - 1 + yy, gx = x0 - 1 + xx;
            u32x4 val = {0,0,0,0};
            if (gy>=0 && gy<HH && gx>=0 && gx<WWID)
                val = *(const u32x4*)(src + (size_t)(gy*WWID+gx)*CC + ch*8);
            int byte = (row*256 + ch*16) ^ ((row&7)<<4);
            *(u32x4*)((char*)lt + byte) = val;
        }
        __syncthreads();

        int cinoff = s*128;
        for (int tap=0; tap<9; ++tap) {
            int dy = tap/3, dx = tap - dy*3;
            const short* wt = WT + ((tap*128 + wr*64 + l15)*256 + cinoff + hi*8);
            #pragma unroll
            for (int kk=0; kk<4; ++kk) {
                bf16x8 av[4];
                #pragma unroll
                for (int m=0;m<4;++m)
                    av[m] = *(const bf16x8*)(wt + m*16*256 + kk*32);
                bf16x8 bv[4];
                #pragma unroll
                for (int n=0;n<4;++n) {
                    int pos = (wc*4 + n + dy)*18 + dx + l15;
                    int byte = (pos*256 + kk*64 + hi*16) ^ ((pos&7)<<4);
                    bv[n] = *(const bf16x8*)((const char*)lt + byte);
                }
                #pragma unroll
                for (int m=0;m<4;++m)
                    #pragma unroll
                    for (int n=0;n<4;++n)
                        acc[m][n] = __builtin_amdgcn_mfma_f32_16x16x32_bf16(
                            av[m], bv[n], acc[m][n], 0, 0, 0);
            }
        }
    }

    short* outp = outT + (size_t)(b*n_l1 + l1)*HW*CC;
    const short* up = (ACT==1) ? uT_in + (size_t)(b*n_l1 + l1)*HW*CC : nullptr;
    #pragma unroll
    for (int m=0;m<4;++m) {
        f32x4 b4 = *(const f32x4*)(bias + wr*64 + m*16 + hi*4);
        #pragma unroll
        for (int n=0;n<4;++n) {
            int pix = (y0 + wc*4 + n)*WWID + x0 + l15;
            int oc  = wr*64 + m*16 + hi*4;
            f32x4 v = acc[m][n] + b4;
            float r[4];
            if (ACT == 0) {
                #pragma unroll
                for (int j=0;j<4;++j) r[j] = 1.f/(1.f + expf(-v[j]));
            } else {
                short4v u4 = *(const short4v*)(up + (size_t)pix*CC + oc);
                #pragma unroll
                for (int j=0;j<4;++j) r[j] = tanhf(v[j]) * b2f(u4[j]);
            }
            u32x2 pk;
            pk[0] = (unsigned int)f2b(r[0]) | ((unsigned int)f2b(r[1])<<16);
            pk[1] = (unsigned int)f2b(r[2]) | ((unsigned int)f2b(r[3])<<16);
            *(u32x2*)(outp + (size_t)pix*CC + oc) = pk;
        }
    }
}

// ---------------------------------------------------------------------------
// final 1x1 MLP:  out[b][oc][pix] = sum_c feat2T[b][pix][c]*W[oc][c] + bias
// ---------------------------------------------------------------------------
__global__ __launch_bounds__(256)
void mlp_kernel(const short* __restrict__ feat2T, const float* __restrict__ Wm,
                const float* __restrict__ bmlp, float* __restrict__ out)
{
    int b = blockIdx.z, oc0 = blockIdx.y*32;
    int pix = blockIdx.x*256 + threadIdx.x;
    const short* src = feat2T + (size_t)b*HW*CC + (size_t)pix*CC;
    float acc[32];
    #pragma unroll
    for (int oc=0;oc<32;++oc) acc[oc]=0.f;
    for (int c8 = 0; c8 < 16; ++c8) {
        bf16x8 v = *(const bf16x8*)(src + c8*8);
        float f[8];
        #pragma unroll
        for (int j=0;j<8;++j) f[j] = b2f(v[j]);
        #pragma unroll
        for (int oc=0; oc<32; ++oc) {
            const float* w = Wm + (size_t)(oc0+oc)*CC + c8*8;
            #pragma unroll
            for (int j=0;j<8;++j) acc[oc] = fmaf(f[j], w[j], acc[oc]);
        }
    }
    #pragma unroll
    for (int oc=0;oc<32;++oc)
        out[((size_t)b*CC + oc0+oc)*HW + pix] = acc[oc] + bmlp[oc0+oc];
}

// ---------------------------------------------------------------------------
extern "C" void kernel_launch(void* const* d_in, const int* in_sizes, int n_in,
                              void* d_out, int out_size, void* d_ws, size_t ws_size,
                              hipStream_t stream)
{
    const float* x     = (const float*)d_in[0];
    const float* mask  = (const float*)d_in[1];
    const float* T     = (const float*)d_in[2];
    const int*   recl  = (const int*)  d_in[3];
    const float* Wmsg  = (const float*)d_in[4];
    const float* bmsg  = (const float*)d_in[5];
    const float* Wg    = (const float*)d_in[6];
    const float* bg    = (const float*)d_in[7];
    const float* Wc    = (const float*)d_in[8];
    const float* bc    = (const float*)d_in[9];
    const float* Wmlp  = (const float*)d_in[10];
    const float* bmlp  = (const float*)d_in[11];
    float* out = (float*)d_out;

    char* w = (char*)d_ws;
    float* ainv = (float*)w;          w += 1024;
    short* xT   = (short*)w;          w += (size_t)BB*LL*HW*CC*2;
    float* fac  = (float*)w;          w += (size_t)32*HW*4;
    short* WmT  = (short*)w;          w += (size_t)9*128*256*2;
    short* WuT  = (short*)w;          w += (size_t)9*128*256*2;
    short* WcT  = (short*)w;          w += (size_t)9*128*256*2;
    short* aggT = (short*)w;          w += (size_t)BB*LL*HW*CC*2;
    short* uT   = (short*)w;          w += (size_t)BB*LL*HW*CC*2;
    short* f1T  = (short*)w;          w += (size_t)BB*LL*HW*CC*2;
    short* f2T  = (short*)w;          w += (size_t)BB*HW*CC*2;

    ainv_kernel<<<1, 64, 0, stream>>>(T, ainv);
    repack_kernel<<<1152, 256, 0, stream>>>(Wmsg, WmT, 0,   256);
    repack_kernel<<<1152, 256, 0, stream>>>(Wg,   WuT, 128, 384);
    repack_kernel<<<1152, 256, 0, stream>>>(Wc,   WcT, 0,   384);
    to_bf16T_kernel<<<dim3(33, BB*LL), 256, 0, stream>>>(x, xT);
    fac_kernel<<<dim3(33, 32), 256, 0, stream>>>(ainv, mask, fac);

    // ---- iteration 1 ----
    msg_mfma_kernel<<<dim3(66,1,BB*LL), 256, 0, stream>>>(
        xT, ainv, fac, mask, recl, WmT, bmsg, aggT, LL);
    gru_mfma_kernel<0><<<dim3(66,1,BB*LL), 256, 0, stream>>>(
        xT, aggT, mask, WuT, bg + CC, nullptr, uT, LL);
    gru_mfma_kernel<1><<<dim3(66,1,BB*LL), 256, 0, stream>>>(
        xT, aggT, mask, WcT, bc, uT, f1T, LL);

    // ---- iteration 2 (only l1=0 consumed) ----
    msg_mfma_kernel<<<dim3(66,1,BB), 256, 0, stream>>>(
        f1T, ainv, fac, mask, recl, WmT, bmsg, aggT, 1);
    gru_mfma_kernel<0><<<dim3(66,1,BB), 256, 0, stream>>>(
        f1T, aggT, mask, WuT, bg + CC, nullptr, uT, 1);
    gru_mfma_kernel<1><<<dim3(66,1,BB), 256, 0, stream>>>(
        f1T, aggT, mask, WcT, bc, uT, f2T, 1);

    // ---- final MLP ----
    mlp_kernel<<<dim3(33,4,BB), 256, 0, stream>>>(f2T, Wmlp, bmlp, out);
}